// Round 2
// baseline (128.184 us; speedup 1.0000x reference)
//
#include <hip/hip_runtime.h>

// NCC (local normalized cross-correlation) loss, win=9^3, SAME zero padding.
// Volume: (B=2, C=1, D=160, H=192, W=160) fp32. Output: scalar fp32 loss.
//
// v2: ring-less z-streaming (re-load departing slice from L2/L3), float4
// column loads (144 vector column tasks), 4-phase LDS pipeline with padded
// strides (Zq stride 28, Rq stride 20, Sq [16][17]) and a sliding y-boxsum
// phase to cut LDS read traffic from ~61 KB to ~30 KB per block-step.

#define NX 160
#define NY 192
#define NZ 160
#define NB 2
#define SLICE (NX * NY)           // 30720
#define VOL   (SLICE * NZ)        // 4915200
#define TOTAL (VOL * NB)          // 9830400

#define TX 16
#define TY 16
#define ZC 32
#define GX (NX / TX)              // 10
#define GY (NY / TY)              // 12
#define GZ (NZ / ZC)              // 5
#define NPART (GX * GY * GZ * NB) // 1200

#define HALO 24                   // TX + 8
#define ZQS 28                    // padded Zq row stride (words), 112B = 16B-aligned rows
#define RQS 20                    // padded Rq row stride (words), 80B  = 16B-aligned rows
#define INV729 (1.0f / 729.0f)

__global__ __launch_bounds__(256) void ncc_main(
    const float* __restrict__ J_pred,   // predict
    const float* __restrict__ I_targ,   // target
    float* __restrict__ partial)
{
    const int tid = threadIdx.x;
    const int x0 = blockIdx.x * TX;
    const int y0 = blockIdx.y * TY;
    const int b  = blockIdx.z / GZ;
    const int z0 = (blockIdx.z % GZ) * ZC;

    __shared__ __align__(16) float Zq[5][HALO * ZQS];   // 13440 B
    __shared__ __align__(16) float Rq[5][HALO][RQS];    //  9600 B
    __shared__ float Sq[5][TY][TX + 1];                 //  5440 B
    __shared__ float redbuf[4];

    // ---- vector-column ownership: 144 tasks, 4 consecutive x-columns each ----
    const bool is_col = (tid < 144);
    const int  crow = tid / 6;          // 0..23 (halo row)
    const int  cxq  = tid - crow * 6;   // 0..5  (float4 group in row)
    const int  gy = y0 - 4 + crow;
    const int  gx = x0 - 4 + cxq * 4;   // multiple of 4 -> float4 fully valid or fully OOB
    const bool vxy = is_col && ((unsigned)gy < (unsigned)NY) && (gx >= 0) && (gx <= NX - 4);
    const size_t cbase = vxy ? ((size_t)b * VOL + (size_t)(gy * NX + gx)) : 0;

    // ---- running z-box-sums per owned column (20 regs, no ring) ----
    float rI[4], rJ[4], rI2[4], rJ2[4], rIJ[4];
#pragma unroll
    for (int c = 0; c < 4; ++c) { rI[c] = rJ[c] = rI2[c] = rJ2[c] = rIJ[c] = 0.f; }

    auto step_cols = [&](int za, int zs, bool dosub) {
        float aI[4] = {0.f, 0.f, 0.f, 0.f}, aJ[4] = {0.f, 0.f, 0.f, 0.f};
        float sI[4] = {0.f, 0.f, 0.f, 0.f}, sJ[4] = {0.f, 0.f, 0.f, 0.f};
        if (vxy) {
            if ((unsigned)za < (unsigned)NZ) {
                const float4 i4 = *(const float4*)(I_targ + cbase + (size_t)za * SLICE);
                const float4 j4 = *(const float4*)(J_pred + cbase + (size_t)za * SLICE);
                aI[0] = i4.x; aI[1] = i4.y; aI[2] = i4.z; aI[3] = i4.w;
                aJ[0] = j4.x; aJ[1] = j4.y; aJ[2] = j4.z; aJ[3] = j4.w;
            }
            if (dosub && (unsigned)zs < (unsigned)NZ) {
                const float4 i4 = *(const float4*)(I_targ + cbase + (size_t)zs * SLICE);
                const float4 j4 = *(const float4*)(J_pred + cbase + (size_t)zs * SLICE);
                sI[0] = i4.x; sI[1] = i4.y; sI[2] = i4.z; sI[3] = i4.w;
                sJ[0] = j4.x; sJ[1] = j4.y; sJ[2] = j4.z; sJ[3] = j4.w;
            }
        }
#pragma unroll
        for (int c = 0; c < 4; ++c) {
            rI[c]  += aI[c] - sI[c];
            rJ[c]  += aJ[c] - sJ[c];
            rI2[c] += aI[c] * aI[c] - sI[c] * sI[c];
            rJ2[c] += aJ[c] * aJ[c] - sJ[c] * sJ[c];
            rIJ[c] += aI[c] * aJ[c] - sI[c] * sJ[c];
        }
    };

    // ---- warm up: add slices z0-5 .. z0+3 (9 add-only steps; OOB z -> zeros).
    // Main loop then always subtracts z0+so-5; at so=0 that exactly removes the
    // z0-5 slice added here (fp re-association error ~1e-6, well under threshold).
#pragma unroll 1
    for (int s = 0; s < 9; ++s) step_cols(z0 - 5 + s, 0, false);

    const int ty = tid >> 4, tx = tid & 15;
    float acc = 0.f;

#pragma unroll 1
    for (int so = 0; so < ZC; ++so) {
        // phase 0: z-slide (adds z0+so+4, subtracts z0+so-5)
        step_cols(z0 + 4 + so, z0 + so - 5, true);

        // phase 1: stage z-summed slices (float4 writes, padded stride 28)
        if (is_col) {
            const int o = crow * ZQS + cxq * 4;
            *(float4*)&Zq[0][o] = make_float4(rI[0],  rI[1],  rI[2],  rI[3]);
            *(float4*)&Zq[1][o] = make_float4(rJ[0],  rJ[1],  rJ[2],  rJ[3]);
            *(float4*)&Zq[2][o] = make_float4(rI2[0], rI2[1], rI2[2], rI2[3]);
            *(float4*)&Zq[3][o] = make_float4(rJ2[0], rJ2[1], rJ2[2], rJ2[3]);
            *(float4*)&Zq[4][o] = make_float4(rIJ[0], rIJ[1], rIJ[2], rIJ[3]);
        }
        __syncthreads();

        // phase 2: x-boxsum, 240 tasks = 24 rows x 5 quantities x 2 halves
        if (tid < 240) {
            const int q   = tid / 48;
            const int rem = tid - q * 48;
            const int row = rem >> 1;
            const int h   = rem & 1;
            const float* src = &Zq[q][row * ZQS + h * 8];
            const float4 v0 = *(const float4*)(src + 0);
            const float4 v1 = *(const float4*)(src + 4);
            const float4 v2 = *(const float4*)(src + 8);
            const float4 v3 = *(const float4*)(src + 12);
            const float c_[16] = { v0.x, v0.y, v0.z, v0.w, v1.x, v1.y, v1.z, v1.w,
                                   v2.x, v2.y, v2.z, v2.w, v3.x, v3.y, v3.z, v3.w };
            float s = c_[0] + c_[1] + c_[2] + c_[3] + c_[4]
                    + c_[5] + c_[6] + c_[7] + c_[8];
            float o[8];
            o[0] = s;
#pragma unroll
            for (int i = 1; i < 8; ++i) { s += c_[i + 8] - c_[i - 1]; o[i] = s; }
            *(float4*)(&Rq[q][row][h * 8 + 0]) = make_float4(o[0], o[1], o[2], o[3]);
            *(float4*)(&Rq[q][row][h * 8 + 4]) = make_float4(o[4], o[5], o[6], o[7]);
        }
        __syncthreads();

        // phase 3: y-boxsum sliding, 160 tasks = 5 q x 16 cols x 2 halves
        if (tid < 160) {
            const int q   = tid / 32;
            const int r2  = tid - q * 32;
            const int tcx = r2 >> 1;
            const int h   = r2 & 1;
            float c_[16];
#pragma unroll
            for (int k = 0; k < 16; ++k) c_[k] = Rq[q][h * 8 + k][tcx];
            float s = c_[0] + c_[1] + c_[2] + c_[3] + c_[4]
                    + c_[5] + c_[6] + c_[7] + c_[8];
            Sq[q][h * 8][tcx] = s;
#pragma unroll
            for (int i = 1; i < 8; ++i) { s += c_[i + 8] - c_[i - 1]; Sq[q][h * 8 + i][tcx] = s; }
        }
        __syncthreads();

        // phase 4: cc per output voxel (all 256 threads)
        const float S0 = Sq[0][ty][tx];
        const float S1 = Sq[1][ty][tx];
        const float S2 = Sq[2][ty][tx];
        const float S3 = Sq[3][ty][tx];
        const float S4 = Sq[4][ty][tx];
        const float cross = S4 - S0 * S1 * INV729;
        const float Iv    = S2 - S0 * S0 * INV729;
        const float Jv    = S3 - S1 * S1 * INV729;
        acc += (cross * cross) / (Iv * Jv + 1e-5f);
        // no barrier needed: next iteration's Sq writes are behind 2 barriers
    }

    // ---- block reduction (deterministic within block) ----
#pragma unroll
    for (int off = 32; off > 0; off >>= 1) acc += __shfl_down(acc, off);
    if ((tid & 63) == 0) redbuf[tid >> 6] = acc;
    __syncthreads();
    if (tid == 0) {
        const int bid = blockIdx.x + GX * (blockIdx.y + GY * blockIdx.z);
        partial[bid] = redbuf[0] + redbuf[1] + redbuf[2] + redbuf[3];
    }
}

__global__ __launch_bounds__(256) void ncc_final(
    const float* __restrict__ partial, float* __restrict__ out)
{
    __shared__ float sm[256];
    const int tid = threadIdx.x;
    float s = 0.f;
    for (int i = tid; i < NPART; i += 256) s += partial[i];
    sm[tid] = s;
    __syncthreads();
#pragma unroll
    for (int w = 128; w > 0; w >>= 1) {
        if (tid < w) sm[tid] += sm[tid + w];
        __syncthreads();
    }
    if (tid == 0) out[0] = 1.0f - sm[0] * (1.0f / (float)TOTAL);
}

extern "C" void kernel_launch(void* const* d_in, const int* in_sizes, int n_in,
                              void* d_out, int out_size, void* d_ws, size_t ws_size,
                              hipStream_t stream)
{
    const float* predict = (const float*)d_in[0];  // J
    const float* target  = (const float*)d_in[1];  // I
    float* partial = (float*)d_ws;                 // 1200 floats (4.8 KB)

    dim3 grid(GX, GY, GZ * NB);
    ncc_main<<<grid, 256, 0, stream>>>(predict, target, partial);
    ncc_final<<<1, 256, 0, stream>>>(partial, (float*)d_out);
}